// Round 3
// baseline (345.632 us; speedup 1.0000x reference)
//
#include <hip/hip_runtime.h>
#include <hip/hip_bf16.h>

// B=32, S=2048, D=1024, C=256
//   top[b,s] = max_c sum_d (latent[c,d]*att_diag[d]) * (tm*embeds[b,s,d] + pos_table[rel+64,d])
//   p = softmax_s(top*m + (m-1)*NEG);  ctx[b,d] = tok_diag[d] * sum_s embeds*p
//
// Pass 1: split-bf16 MFMA emulation. W = latent*att_diag pre-split hi/lo bf16,
// fragment-ordered in ws. Block = 64 tokens; wave wv owns c-tiles [4wv,4wv+4)
// over ALL 64 tokens (4 token-sets) -> W read once per block (1 GB L2 total),
// 12 MFMAs per A-frag pair. Cross-wave max combine via LDS.
//
// ws: whi 512K | wlo 512K | top 256K | probs 256K | partial 2M = 3.5 MB

#define HC 64
#define NEGV 1000000000000.0f

constexpr int Bb = 32, Ss = 2048, Dd = 1024, Cc = 256;
constexpr int KC = 32, NKC = Dd / KC;   // MFMA K chunks
constexpr int CT = Cc / 16;             // 16 c-tiles
constexpr int NSPLIT = 16, SCHUNK = Ss / NSPLIT;

typedef __bf16 bf16x8 __attribute__((ext_vector_type(8)));
typedef float  f32x4  __attribute__((ext_vector_type(4)));

// ---------------- Pass 0: W -> fragment-ordered bf16 hi/lo ----------------
// slot map: lane = (c%16) + 16*g,  k = kc*32 + 8*g + i  (g=0..3,i=0..7)
// dst = ((kc*CT + c/16)*64 + lane)*8 + i
__global__ __launch_bounds__(256) void k_prep_w(
    const float* __restrict__ latent, const float* __restrict__ att_diag,
    __bf16* __restrict__ whi, __bf16* __restrict__ wlo)
{
    const int idx = blockIdx.x * 256 + threadIdx.x;   // c*Dd + k
    const int c = idx >> 10, k = idx & 1023;
    const float w = latent[idx] * att_diag[k];
    const __bf16 h = (__bf16)w;
    const __bf16 lo = (__bf16)(w - (float)h);
    const int kc = k >> 5, kr = k & 31;
    const int g = kr >> 3, i = kr & 7;
    const int lane = (c & 15) + 16 * g;
    const size_t dst = (((size_t)(kc * CT + (c >> 4))) * 64 + lane) * 8 + i;
    whi[dst] = h;
    wlo[dst] = lo;
}

// ---------------- Pass 1: scores via MFMA, max over c ----------------
__global__ __launch_bounds__(256) void k_scores_mfma(
    const float* __restrict__ embeds,    // [B][S][D]
    const float* __restrict__ mask,      // [B][S]
    const float* __restrict__ pos_table, // [132][D]
    const float* __restrict__ tok_mult,  // [1]
    const int*   __restrict__ rel_ids,   // [B][S]
    const __bf16* __restrict__ whi, const __bf16* __restrict__ wlo,
    float* __restrict__ top)             // [B][S]
{
    const int t  = threadIdx.x;
    const int wv = t >> 6;      // wave 0..3 -> c-tiles 4wv..4wv+3
    const int l  = t & 63;
    const int lr = l & 15;      // token within set / output col
    const int lg = l >> 4;      // k-group

    const int blk = blockIdx.x;
    const int b   = blk >> 5;
    const int s0  = (blk & 31) * 64;

    const float tm = tok_mult[0];

    const float* erow[4];
    const float* prow[4];
    #pragma unroll
    for (int set = 0; set < 4; set++) {
        const int tok = s0 + set * 16 + lr;
        erow[set] = embeds + ((size_t)b * Ss + tok) * Dd;
        prow[set] = pos_table + (size_t)(rel_ids[b * Ss + tok] + HC) * Dd;
    }

    f32x4 acc[4][4];   // [ct4][set]
    #pragma unroll
    for (int i = 0; i < 4; i++)
        #pragma unroll
        for (int j = 0; j < 4; j++) acc[i][j] = (f32x4){0.f, 0.f, 0.f, 0.f};

    const bf16x8* whi8 = (const bf16x8*)whi;
    const bf16x8* wlo8 = (const bf16x8*)wlo;

    for (int kc = 0; kc < NKC; kc++) {
        const int k0 = kc * KC + lg * 8;
        bf16x8 bh[4], bl[4];
        #pragma unroll
        for (int set = 0; set < 4; set++) {
            float e[8], p[8];
            *(f32x4*)&e[0] = *(const f32x4*)(erow[set] + k0);
            *(f32x4*)&e[4] = *(const f32x4*)(erow[set] + k0 + 4);
            *(f32x4*)&p[0] = *(const f32x4*)(prow[set] + k0);
            *(f32x4*)&p[4] = *(const f32x4*)(prow[set] + k0 + 4);
            #pragma unroll
            for (int i = 0; i < 8; i++) {
                const float x = fmaf(tm, e[i], p[i]);
                const __bf16 h = (__bf16)x;
                bh[set][i] = h;
                bl[set][i] = (__bf16)(x - (float)h);
            }
        }
        const int fbase = kc * (CT * 64) + l;
        #pragma unroll
        for (int ct4 = 0; ct4 < 4; ct4++) {
            const int ct = wv * 4 + ct4;
            const bf16x8 ah = whi8[fbase + ct * 64];
            const bf16x8 al = wlo8[fbase + ct * 64];
            #pragma unroll
            for (int set = 0; set < 4; set++) {
                acc[ct4][set] = __builtin_amdgcn_mfma_f32_16x16x32_bf16(ah, bh[set], acc[ct4][set], 0, 0, 0);
                acc[ct4][set] = __builtin_amdgcn_mfma_f32_16x16x32_bf16(ah, bl[set], acc[ct4][set], 0, 0, 0);
                acc[ct4][set] = __builtin_amdgcn_mfma_f32_16x16x32_bf16(al, bh[set], acc[ct4][set], 0, 0, 0);
            }
        }
    }

    // per set: max over this wave's 64 c values, combine across waves in LDS
    __shared__ float red[4][64];
    #pragma unroll
    for (int set = 0; set < 4; set++) {
        float mx = acc[0][set][0];
        #pragma unroll
        for (int ct4 = 0; ct4 < 4; ct4++)
            #pragma unroll
            for (int r = 0; r < 4; r++) mx = fmaxf(mx, acc[ct4][set][r]);
        mx = fmaxf(mx, __shfl_xor(mx, 16));
        mx = fmaxf(mx, __shfl_xor(mx, 32));
        if (lg == 0) red[wv][set * 16 + lr] = mx;
    }
    __syncthreads();
    if (t < 64) {
        const float m01 = fmaxf(red[0][t], red[1][t]);
        const float m23 = fmaxf(red[2][t], red[3][t]);
        const float mx  = fmaxf(m01, m23);
        const int s = s0 + t;
        const float mk = mask[b * Ss + s];
        top[b * Ss + s] = mx * mk + (mk - 1.0f) * NEGV;
    }
}

// ---------------- Pass 2: softmax over s ----------------
__global__ __launch_bounds__(256) void k_softmax(
    const float* __restrict__ top, float* __restrict__ probs)
{
    const int b = blockIdx.x, t = threadIdx.x;
    const float* row = top + (size_t)b * Ss;
    float v[8];
    #pragma unroll
    for (int i = 0; i < 8; i++) v[i] = row[t + 256 * i];

    float mx = v[0];
    #pragma unroll
    for (int i = 1; i < 8; i++) mx = fmaxf(mx, v[i]);
    #pragma unroll
    for (int o = 32; o >= 1; o >>= 1) mx = fmaxf(mx, __shfl_xor(mx, o));

    __shared__ float redm[4], reds[4];
    const int w = t >> 6, ln = t & 63;
    if (ln == 0) redm[w] = mx;
    __syncthreads();
    mx = fmaxf(fmaxf(redm[0], redm[1]), fmaxf(redm[2], redm[3]));

    float sum = 0.f;
    #pragma unroll
    for (int i = 0; i < 8; i++) { v[i] = expf(v[i] - mx); sum += v[i]; }
    #pragma unroll
    for (int o = 32; o >= 1; o >>= 1) sum += __shfl_xor(sum, o);
    if (ln == 0) reds[w] = sum;
    __syncthreads();
    sum = reds[0] + reds[1] + reds[2] + reds[3];

    const float inv = 1.0f / sum;
    #pragma unroll
    for (int i = 0; i < 8; i++) probs[(size_t)b * Ss + t + 256 * i] = v[i] * inv;
}

// ---------------- Pass 3: partial context sums ----------------
__global__ __launch_bounds__(256) void k_ctx_partial(
    const float* __restrict__ embeds, const float* __restrict__ probs,
    float* __restrict__ partial)   // [B][NSPLIT][D]
{
    const int b  = blockIdx.x / NSPLIT;
    const int sp = blockIdx.x % NSPLIT;
    const int d  = threadIdx.x * 4;
    const float* base = embeds + ((size_t)b * Ss + sp * SCHUNK) * Dd;
    const float* prow = probs + (size_t)b * Ss + sp * SCHUNK;
    float4 acc = make_float4(0.f, 0.f, 0.f, 0.f);
    for (int s = 0; s < SCHUNK; s++) {
        const float p = prow[s];
        float4 e = *(const float4*)(base + (size_t)s * Dd + d);
        acc.x = fmaf(p, e.x, acc.x);
        acc.y = fmaf(p, e.y, acc.y);
        acc.z = fmaf(p, e.z, acc.z);
        acc.w = fmaf(p, e.w, acc.w);
    }
    *(float4*)(partial + ((size_t)(b * NSPLIT + sp)) * Dd + d) = acc;
}

// ---------------- Pass 4: reduce partials, apply tok_diag ----------------
__global__ __launch_bounds__(256) void k_ctx_reduce(
    const float* __restrict__ partial, const float* __restrict__ tok_diag,
    float* __restrict__ out)  // [B][D]
{
    const int b = blockIdx.x;
    const int d = threadIdx.x * 4;
    float4 acc = make_float4(0.f, 0.f, 0.f, 0.f);
    #pragma unroll
    for (int sp = 0; sp < NSPLIT; sp++) {
        float4 v = *(const float4*)(partial + ((size_t)(b * NSPLIT + sp)) * Dd + d);
        acc.x += v.x; acc.y += v.y; acc.z += v.z; acc.w += v.w;
    }
    float4 td = *(const float4*)(tok_diag + d);
    float4 o = make_float4(acc.x * td.x, acc.y * td.y, acc.z * td.z, acc.w * td.w);
    *(float4*)(out + (size_t)b * Dd + d) = o;
}

extern "C" void kernel_launch(void* const* d_in, const int* in_sizes, int n_in,
                              void* d_out, int out_size, void* d_ws, size_t ws_size,
                              hipStream_t stream) {
    const float* embeds    = (const float*)d_in[0];
    const float* mask      = (const float*)d_in[1];
    const float* latent    = (const float*)d_in[2];
    const float* att_diag  = (const float*)d_in[3];
    const float* tok_diag  = (const float*)d_in[4];
    const float* pos_table = (const float*)d_in[5];
    const float* tok_mult  = (const float*)d_in[6];
    const int*   rel_ids   = (const int*)d_in[7];
    float* out = (float*)d_out;

    char* ws = (char*)d_ws;
    __bf16* whi    = (__bf16*)(ws);                  // 512 KB
    __bf16* wlo    = (__bf16*)(ws + 524288);         // 512 KB
    float*  top    = (float*)(ws + 1048576);         // 256 KB
    float*  probs  = (float*)(ws + 1310720);         // 256 KB
    float*  partial= (float*)(ws + 1572864);         // 2 MB

    k_prep_w<<<(Cc * Dd) / 256, 256, 0, stream>>>(latent, att_diag, whi, wlo);
    k_scores_mfma<<<(Bb * Ss) / 64, 256, 0, stream>>>(
        embeds, mask, pos_table, tok_mult, rel_ids, whi, wlo, top);
    k_softmax<<<Bb, 256, 0, stream>>>(top, probs);
    k_ctx_partial<<<Bb * NSPLIT, 256, 0, stream>>>(embeds, probs, partial);
    k_ctx_reduce<<<Bb, 256, 0, stream>>>(partial, tok_diag, out);
}

// Round 4
// 143.381 us; speedup vs baseline: 2.4106x; 2.4106x over previous
//
#include <hip/hip_runtime.h>
#include <hip/hip_bf16.h>

// B=32, S=2048, D=1024, C=256
//   top[b,s] = max_c sum_d (latent[c,d]*att_diag[d]) * (tm*embeds[b,s,d] + pos_table[rel+64,d])
//   p = softmax_s(top*m + (m-1)*NEG);  ctx[b,d] = tok_diag[d] * sum_s embeds*p
//
// Pass 1: split-fp16 MFMA (3 terms: hh + h*lo + lo*h ~ 22-bit precision).
// W = latent*att_diag pre-split hi/lo fp16, stored as contiguous 32KB per-kc
// chunks. Block = 4 waves, 128 tokens; W staged once per block per kc via
// global_load_lds into double-buffered LDS; wave owns 16 c-tiles x 2 token
// sets -> each LDS frag pair feeds 6 MFMAs. One barrier per kc (m97-style).
//
// ws: w f16 1MB | top 256K | probs 256K | partial 2M

#define HC 64
#define NEGV 1000000000000.0f

constexpr int Bb = 32, Ss = 2048, Dd = 1024, Cc = 256;
constexpr int NKC = 32;                 // k-chunks of 32
constexpr int CT = Cc / 16;             // 16 c-tiles
constexpr int NSPLIT = 16, SCHUNK = Ss / NSPLIT;

typedef _Float16 f16x8 __attribute__((ext_vector_type(8)));
typedef float    f32x4 __attribute__((ext_vector_type(4)));

// ---------------- Pass 0: W -> per-kc fragment chunks, fp16 hi/lo ----------
// layout: w[kc][part][ct][lane][i]  (part 0=hi,1=lo), chunk = 16384 f16 = 32KB
// A-frag hw map: lane = (c%16) + 16*g holds A[c][k= kc*32 + 8g + i]
__global__ __launch_bounds__(256) void k_prep_w(
    const float* __restrict__ latent, const float* __restrict__ att_diag,
    _Float16* __restrict__ w)
{
    const int idx = blockIdx.x * 256 + threadIdx.x;   // c*Dd + k
    const int c = idx >> 10, k = idx & 1023;
    const float wv = latent[idx] * att_diag[k];
    const _Float16 h  = (_Float16)wv;
    const _Float16 lo = (_Float16)(wv - (float)h);
    const int kc = k >> 5, g = (k >> 3) & 3, i = k & 7;
    const int lane = (c & 15) + 16 * g, ct = c >> 4;
    const size_t base = (size_t)kc * 16384 + (size_t)ct * 512 + lane * 8 + i;
    w[base]        = h;     // hi region [0,8192)
    w[base + 8192] = lo;    // lo region
}

// ---------------- Pass 1: scores via MFMA, max over c ----------------
__global__ __launch_bounds__(256, 2) void k_scores_mfma(
    const float* __restrict__ embeds,    // [B][S][D]
    const float* __restrict__ mask,      // [B][S]
    const float* __restrict__ pos_table, // [132][D]
    const float* __restrict__ tok_mult,  // [1]
    const int*   __restrict__ rel_ids,   // [B][S]
    const _Float16* __restrict__ w,      // [NKC][2][CT][64][8]
    float* __restrict__ top)             // [B][S]
{
    __shared__ _Float16 sbuf[2][16384];  // 2 x 32KB

    const int t  = threadIdx.x;
    const int wv = t >> 6;      // wave 0..3
    const int l  = t & 63;
    const int lr = l & 15;      // token within set / output col
    const int lg = l >> 4;      // k-group

    const int b  = blockIdx.x >> 4;          // 16 blocks of 128 tokens per batch
    const int s0 = (blockIdx.x & 15) * 128;

    const float tm = tok_mult[0];

    const float* erow[2];
    const float* prow[2];
    #pragma unroll
    for (int st = 0; st < 2; st++) {
        const int tok = s0 + wv * 32 + st * 16 + lr;
        erow[st] = embeds + ((size_t)b * Ss + tok) * Dd;
        prow[st] = pos_table + (size_t)(rel_ids[b * Ss + tok] + HC) * Dd;
    }

    f32x4 acc[CT][2];
    #pragma unroll
    for (int ct = 0; ct < CT; ct++)
        #pragma unroll
        for (int st = 0; st < 2; st++) acc[ct][st] = (f32x4){0.f, 0.f, 0.f, 0.f};

    // raw e/p prefetch registers (one kc ahead)
    f32x4 e0[2], e1[2], p0[2], p1[2];
    auto loadEP = [&](int kc) {
        const int k0 = kc * 32 + lg * 8;
        #pragma unroll
        for (int st = 0; st < 2; st++) {
            e0[st] = *(const f32x4*)(erow[st] + k0);
            e1[st] = *(const f32x4*)(erow[st] + k0 + 4);
            p0[st] = *(const f32x4*)(prow[st] + k0);
            p1[st] = *(const f32x4*)(prow[st] + k0 + 4);
        }
    };

    // stage one 32KB W chunk: 32 wave-chunks of 1KB (8 per wave)
    auto stage = [&](int kc, _Float16* dst) {
        const _Float16* src = w + (size_t)kc * 16384;
        #pragma unroll
        for (int i = 0; i < 8; i++) {
            const int off = (i * 4 + wv) << 9;   // elems; 1KB chunks
            __builtin_amdgcn_global_load_lds(
                (const __attribute__((address_space(1))) void*)(src + off + l * 8),
                (__attribute__((address_space(3))) void*)(dst + off),
                16, 0, 0);
        }
    };

    loadEP(0);
    stage(0, sbuf[0]);
    __syncthreads();   // drains vmcnt: stage(0) + loadEP(0) complete

    int cur = 0;
    for (int kc = 0; kc < NKC; kc++) {
        if (kc + 1 < NKC) stage(kc + 1, sbuf[cur ^ 1]);

        // build current B frags (hi/lo fp16) from prefetched raws
        f16x8 bh[2], bl[2];
        #pragma unroll
        for (int st = 0; st < 2; st++) {
            float e[8], p[8];
            *(f32x4*)&e[0] = e0[st]; *(f32x4*)&e[4] = e1[st];
            *(f32x4*)&p[0] = p0[st]; *(f32x4*)&p[4] = p1[st];
            #pragma unroll
            for (int i = 0; i < 8; i++) {
                const float x = fmaf(tm, e[i], p[i]);
                const _Float16 h = (_Float16)x;
                bh[st][i] = h;
                bl[st][i] = (_Float16)(x - (float)h);
            }
        }
        if (kc + 1 < NKC) loadEP(kc + 1);   // issue next-kc e/p early

        const _Float16* base = sbuf[cur];
        #pragma unroll
        for (int ct = 0; ct < CT; ct++) {
            const f16x8 ah = *(const f16x8*)(base + ct * 512 + l * 8);
            const f16x8 al = *(const f16x8*)(base + 8192 + ct * 512 + l * 8);
            #pragma unroll
            for (int st = 0; st < 2; st++) {
                acc[ct][st] = __builtin_amdgcn_mfma_f32_16x16x32_f16(ah, bh[st], acc[ct][st], 0, 0, 0);
                acc[ct][st] = __builtin_amdgcn_mfma_f32_16x16x32_f16(ah, bl[st], acc[ct][st], 0, 0, 0);
                acc[ct][st] = __builtin_amdgcn_mfma_f32_16x16x32_f16(al, bh[st], acc[ct][st], 0, 0, 0);
            }
        }
        __syncthreads();   // stage(kc+1) done; all waves done reading sbuf[cur]
        cur ^= 1;
    }

    // max over c per token (C/D map: col=lane&15, row=(lane>>4)*4+reg)
    #pragma unroll
    for (int st = 0; st < 2; st++) {
        float mx = acc[0][st][0];
        #pragma unroll
        for (int ct = 0; ct < CT; ct++)
            #pragma unroll
            for (int r = 0; r < 4; r++) mx = fmaxf(mx, acc[ct][st][r]);
        mx = fmaxf(mx, __shfl_xor(mx, 16));
        mx = fmaxf(mx, __shfl_xor(mx, 32));
        if (lg == 0) {
            const int s = s0 + wv * 32 + st * 16 + lr;
            const float mk = mask[b * Ss + s];
            top[b * Ss + s] = mx * mk + (mk - 1.0f) * NEGV;
        }
    }
}

// ---------------- Pass 2: softmax over s ----------------
__global__ __launch_bounds__(256) void k_softmax(
    const float* __restrict__ top, float* __restrict__ probs)
{
    const int b = blockIdx.x, t = threadIdx.x;
    const float* row = top + (size_t)b * Ss;
    float v[8];
    #pragma unroll
    for (int i = 0; i < 8; i++) v[i] = row[t + 256 * i];

    float mx = v[0];
    #pragma unroll
    for (int i = 1; i < 8; i++) mx = fmaxf(mx, v[i]);
    #pragma unroll
    for (int o = 32; o >= 1; o >>= 1) mx = fmaxf(mx, __shfl_xor(mx, o));

    __shared__ float redm[4], reds[4];
    const int w = t >> 6, ln = t & 63;
    if (ln == 0) redm[w] = mx;
    __syncthreads();
    mx = fmaxf(fmaxf(redm[0], redm[1]), fmaxf(redm[2], redm[3]));

    float sum = 0.f;
    #pragma unroll
    for (int i = 0; i < 8; i++) { v[i] = expf(v[i] - mx); sum += v[i]; }
    #pragma unroll
    for (int o = 32; o >= 1; o >>= 1) sum += __shfl_xor(sum, o);
    if (ln == 0) reds[w] = sum;
    __syncthreads();
    sum = reds[0] + reds[1] + reds[2] + reds[3];

    const float inv = 1.0f / sum;
    #pragma unroll
    for (int i = 0; i < 8; i++) probs[(size_t)b * Ss + t + 256 * i] = v[i] * inv;
}

// ---------------- Pass 3: partial context sums ----------------
__global__ __launch_bounds__(256) void k_ctx_partial(
    const float* __restrict__ embeds, const float* __restrict__ probs,
    float* __restrict__ partial)   // [B][NSPLIT][D]
{
    const int b  = blockIdx.x / NSPLIT;
    const int sp = blockIdx.x % NSPLIT;
    const int d  = threadIdx.x * 4;
    const float* base = embeds + ((size_t)b * Ss + sp * SCHUNK) * Dd;
    const float* prow = probs + (size_t)b * Ss + sp * SCHUNK;
    float4 acc = make_float4(0.f, 0.f, 0.f, 0.f);
    for (int s = 0; s < SCHUNK; s++) {
        const float p = prow[s];
        float4 e = *(const float4*)(base + (size_t)s * Dd + d);
        acc.x = fmaf(p, e.x, acc.x);
        acc.y = fmaf(p, e.y, acc.y);
        acc.z = fmaf(p, e.z, acc.z);
        acc.w = fmaf(p, e.w, acc.w);
    }
    *(float4*)(partial + ((size_t)(b * NSPLIT + sp)) * Dd + d) = acc;
}

// ---------------- Pass 4: reduce partials, apply tok_diag ----------------
__global__ __launch_bounds__(256) void k_ctx_reduce(
    const float* __restrict__ partial, const float* __restrict__ tok_diag,
    float* __restrict__ out)  // [B][D]
{
    const int b = blockIdx.x;
    const int d = threadIdx.x * 4;
    float4 acc = make_float4(0.f, 0.f, 0.f, 0.f);
    #pragma unroll
    for (int sp = 0; sp < NSPLIT; sp++) {
        float4 v = *(const float4*)(partial + ((size_t)(b * NSPLIT + sp)) * Dd + d);
        acc.x += v.x; acc.y += v.y; acc.z += v.z; acc.w += v.w;
    }
    float4 td = *(const float4*)(tok_diag + d);
    float4 o = make_float4(acc.x * td.x, acc.y * td.y, acc.z * td.z, acc.w * td.w);
    *(float4*)(out + (size_t)b * Dd + d) = o;
}

extern "C" void kernel_launch(void* const* d_in, const int* in_sizes, int n_in,
                              void* d_out, int out_size, void* d_ws, size_t ws_size,
                              hipStream_t stream) {
    const float* embeds    = (const float*)d_in[0];
    const float* mask      = (const float*)d_in[1];
    const float* latent    = (const float*)d_in[2];
    const float* att_diag  = (const float*)d_in[3];
    const float* tok_diag  = (const float*)d_in[4];
    const float* pos_table = (const float*)d_in[5];
    const float* tok_mult  = (const float*)d_in[6];
    const int*   rel_ids   = (const int*)d_in[7];
    float* out = (float*)d_out;

    char* ws = (char*)d_ws;
    _Float16* w      = (_Float16*)(ws);              // 1 MB
    float*    top    = (float*)(ws + 1048576);       // 256 KB
    float*    probs  = (float*)(ws + 1310720);       // 256 KB
    float*    partial= (float*)(ws + 1572864);       // 2 MB

    k_prep_w<<<(Cc * Dd) / 256, 256, 0, stream>>>(latent, att_diag, w);
    k_scores_mfma<<<(Bb * Ss) / 128, 256, 0, stream>>>(
        embeds, mask, pos_table, tok_mult, rel_ids, w, top);
    k_softmax<<<Bb, 256, 0, stream>>>(top, probs);
    k_ctx_partial<<<Bb * NSPLIT, 256, 0, stream>>>(embeds, probs, partial);
    k_ctx_reduce<<<Bb, 256, 0, stream>>>(partial, tok_diag, out);
}